// Round 1
// baseline (568.123 us; speedup 1.0000x reference)
//
#include <hip/hip_runtime.h>

// DCTPolicy: coeffs = scatter(mean + exp(log_std)*eps), log_prob, entropy.
// Gather formulation: each block = 8 rows x 512 cols strip = 64 8x8 tiles,
// 1024 contiguous params. Params staged in LDS (stride-17 pad), outputs
// written exactly once with coalesced float4 stores. flat_idx input unused
// (index map is deterministic: zigzag rank table below).

constexpr int W = 4096;
constexpr int H = 4096;
constexpr long long CHW = 3LL * 4096 * 4096;           // 50331648
constexpr float LOG2PI = 1.8378770664093453f;          // ln(2*pi)

// RT[u] = ranks for row u of an 8x8 block, byte v = zigzag rank of (u,v),
// 0xFF = not among first 16 zigzag coefficients.
// zigzag(B=8)[0:16]: (0,0)(1,0)(0,1)(0,2)(1,1)(2,0)(3,0)(2,1)(1,2)(0,3)
//                    (0,4)(1,3)(2,2)(3,1)(4,0)(5,0)
__device__ __constant__ unsigned long long RT[8] = {
    0xFFFFFF0A09030200ull,  // u=0: v0=0 v1=2 v2=3 v3=9 v4=10
    0xFFFFFFFF0B080401ull,  // u=1: v0=1 v1=4 v2=8 v3=11
    0xFFFFFFFFFF0C0705ull,  // u=2: v0=5 v1=7 v2=12
    0xFFFFFFFFFFFF0D06ull,  // u=3: v0=6 v1=13
    0xFFFFFFFFFFFFFF0Eull,  // u=4: v0=14
    0xFFFFFFFFFFFFFF0Full,  // u=5: v0=15
    0xFFFFFFFFFFFFFFFFull,  // u=6: none
    0xFFFFFFFFFFFFFFFFull   // u=7: none
};

__global__ __launch_bounds__(256) void dct_policy_kernel(
    const float* __restrict__ mean,
    const float* __restrict__ log_std,
    const float* __restrict__ eps,
    float* __restrict__ out)
{
    // 64 tiles * 16 samples, leading-dim padded 16->17 to break bank conflicts
    __shared__ float smp[64 * 17];
    __shared__ float p1[4], p2[4];

    const int t   = threadIdx.x;          // 0..255
    const int bid = blockIdx.x;           // 0..12287
    const int c   = bid >> 12;            // channel (4096 blocks per channel)
    const int rem = bid & 4095;
    const int bh  = rem >> 3;             // tile row 0..511
    const int sx  = rem & 7;              // 512-wide strip index 0..7

    // ---- Phase 1: load 1024 contiguous params, compute samples into LDS ----
    const long long pbase = (long long)(c * 512 + bh) * 8192 + (long long)sx * 1024;

    const float4 m4 = *(const float4*)(mean    + pbase + 4 * t);
    const float4 l4 = *(const float4*)(log_std + pbase + 4 * t);
    const float4 e4 = *(const float4*)(eps     + pbase + 4 * t);

    const float mv[4] = {m4.x, m4.y, m4.z, m4.w};
    const float lv[4] = {l4.x, l4.y, l4.z, l4.w};
    const float ev[4] = {e4.x, e4.y, e4.z, e4.w};

    float s1 = 0.f, s2 = 0.f;   // sum(eps^2), sum(log_std)
#pragma unroll
    for (int j = 0; j < 4; ++j) {
        const int idx  = 4 * t + j;          // param within strip 0..1023
        const int tile = idx >> 4;           // 0..63
        const int rank = idx & 15;           // 0..15
        const float s  = mv[j] + __builtin_expf(lv[j]) * ev[j]; // COEFF_SCALE=1
        smp[tile * 17 + rank] = s;
        s1 += ev[j] * ev[j];
        s2 += lv[j];
    }

    // wave(64) butterfly reduce
#pragma unroll
    for (int off = 32; off > 0; off >>= 1) {
        s1 += __shfl_xor(s1, off, 64);
        s2 += __shfl_xor(s2, off, 64);
    }
    if ((t & 63) == 0) { p1[t >> 6] = s1; p2[t >> 6] = s2; }

    __syncthreads();   // covers both smp[] and p1/p2

    if (t == 0) {
        const float S1 = p1[0] + p1[1] + p1[2] + p1[3];
        const float S2 = p2[0] + p2[1] + p2[2] + p2[3];
        // log_prob: -0.5*sum(eps^2 + 2*log_std + log2pi)
        unsafeAtomicAdd(out + CHW,     -0.5f * S1 - S2 - 0.5f * 1024.0f * LOG2PI);
        // entropy: sum(0.5*(1+log2pi) + log_std)
        unsafeAtomicAdd(out + CHW + 1, 1024.0f * 0.5f * (1.0f + LOG2PI) + S2);
    }

    // ---- Phase 2: write 8x512 strip, each output exactly once (float4) ----
    const long long obase = (long long)c * ((long long)H * W)
                          + (long long)(bh * 8) * W + sx * 512;
#pragma unroll
    for (int q = 0; q < 4; ++q) {
        const int f    = t + 256 * q;        // 0..1023 float4 slots
        const int u    = f >> 7;             // row in strip 0..7 (wave-uniform)
        const int x4   = f & 127;            // float4 col 0..127
        const int tile = x4 >> 1;            // 0..63
        const int vb   = (x4 & 1) * 4;       // v base 0 or 4
        const unsigned long long row = RT[u];
        float4 o;
        float* ov = (float*)&o;
#pragma unroll
        for (int j = 0; j < 4; ++j) {
            const unsigned r = (unsigned)((row >> (8 * (vb + j))) & 0xFFull);
            // clamp address so the speculative LDS read stays in-bounds
            const float v = smp[tile * 17 + (int)(r & 15u)];
            ov[j] = (r != 0xFFu) ? v : 0.0f;
        }
        *(float4*)(out + obase + (long long)u * W + x4 * 4) = o;
    }
}

extern "C" void kernel_launch(void* const* d_in, const int* in_sizes, int n_in,
                              void* d_out, int out_size, void* d_ws, size_t ws_size,
                              hipStream_t stream) {
    const float* mean    = (const float*)d_in[0];
    const float* log_std = (const float*)d_in[1];
    const float* eps     = (const float*)d_in[2];
    // d_in[3] (flat_idx) intentionally unused: mapping computed arithmetically.
    float* out = (float*)d_out;

    // zero the two scalar accumulators (coeffs region is fully overwritten)
    hipMemsetAsync((char*)d_out + (size_t)CHW * 4, 0, 2 * sizeof(float), stream);

    // 3 channels * 512 tile-rows * 8 strips = 12288 blocks
    dct_policy_kernel<<<12288, 256, 0, stream>>>(mean, log_std, eps, out);
}

// Round 2
// 339.853 us; speedup vs baseline: 1.6717x; 1.6717x over previous
//
#include <hip/hip_runtime.h>

// DCTPolicy: coeffs = scatter(mean + exp(log_std)*eps), log_prob, entropy.
// Gather formulation: each block = 8 rows x 512 cols strip = 64 8x8 tiles,
// 1024 contiguous params. Params staged in LDS (stride-17 pad), outputs
// written exactly once with coalesced float4 stores. flat_idx input unused.
//
// R1 change: same-address atomics (24576 to 2 addresses) replaced by
// per-block partials in d_ws + a tiny reduction kernel. R0 showed 860 GB/s
// at 6% VALUBusy -> atomic serialization backpressure suspected.

constexpr int W = 4096;
constexpr int H = 4096;
constexpr long long CHW = 3LL * 4096 * 4096;           // 50331648
constexpr float LOG2PI = 1.8378770664093453f;          // ln(2*pi)
constexpr int NBLK = 12288;
constexpr float NTOT = 12582912.0f;                    // C*NH*NW*K

// RT[u] = ranks for row u of an 8x8 block, byte v = zigzag rank of (u,v),
// 0xFF = not among first 16 zigzag coefficients.
__device__ __constant__ unsigned long long RT[8] = {
    0xFFFFFF0A09030200ull,  // u=0: v0=0 v1=2 v2=3 v3=9 v4=10
    0xFFFFFFFF0B080401ull,  // u=1: v0=1 v1=4 v2=8 v3=11
    0xFFFFFFFFFF0C0705ull,  // u=2: v0=5 v1=7 v2=12
    0xFFFFFFFFFFFF0D06ull,  // u=3: v0=6 v1=13
    0xFFFFFFFFFFFFFF0Eull,  // u=4: v0=14
    0xFFFFFFFFFFFFFF0Full,  // u=5: v0=15
    0xFFFFFFFFFFFFFFFFull,  // u=6: none
    0xFFFFFFFFFFFFFFFFull   // u=7: none
};

__global__ __launch_bounds__(256) void dct_policy_kernel(
    const float* __restrict__ mean,
    const float* __restrict__ log_std,
    const float* __restrict__ eps,
    float* __restrict__ out,
    float2* __restrict__ partials)
{
    __shared__ float smp[64 * 17];
    __shared__ float p1[4], p2[4];

    const int t   = threadIdx.x;          // 0..255
    const int bid = blockIdx.x;           // 0..12287
    const int c   = bid >> 12;
    const int rem = bid & 4095;
    const int bh  = rem >> 3;             // tile row 0..511
    const int sx  = rem & 7;              // 512-wide strip 0..7

    // ---- Phase 1: load 1024 contiguous params, compute samples into LDS ----
    const long long pbase = (long long)(c * 512 + bh) * 8192 + (long long)sx * 1024;

    const float4 m4 = *(const float4*)(mean    + pbase + 4 * t);
    const float4 l4 = *(const float4*)(log_std + pbase + 4 * t);
    const float4 e4 = *(const float4*)(eps     + pbase + 4 * t);

    const float mv[4] = {m4.x, m4.y, m4.z, m4.w};
    const float lv[4] = {l4.x, l4.y, l4.z, l4.w};
    const float ev[4] = {e4.x, e4.y, e4.z, e4.w};

    float s1 = 0.f, s2 = 0.f;
#pragma unroll
    for (int j = 0; j < 4; ++j) {
        const int idx  = 4 * t + j;
        const int tile = idx >> 4;
        const int rank = idx & 15;
        const float s  = mv[j] + __builtin_expf(lv[j]) * ev[j]; // COEFF_SCALE=1
        smp[tile * 17 + rank] = s;
        s1 += ev[j] * ev[j];
        s2 += lv[j];
    }

#pragma unroll
    for (int off = 32; off > 0; off >>= 1) {
        s1 += __shfl_xor(s1, off, 64);
        s2 += __shfl_xor(s2, off, 64);
    }
    if ((t & 63) == 0) { p1[t >> 6] = s1; p2[t >> 6] = s2; }

    __syncthreads();   // covers both smp[] and p1/p2

    if (t == 0) {
        partials[bid] = make_float2(p1[0] + p1[1] + p1[2] + p1[3],
                                    p2[0] + p2[1] + p2[2] + p2[3]);
    }

    // ---- Phase 2: write 8x512 strip, each output exactly once (float4) ----
    const long long obase = (long long)c * ((long long)H * W)
                          + (long long)(bh * 8) * W + sx * 512;
#pragma unroll
    for (int q = 0; q < 4; ++q) {
        const int f    = t + 256 * q;        // 0..1023 float4 slots
        const int u    = f >> 7;             // row 0..7 (wave-uniform)
        const int x4   = f & 127;            // float4 col 0..127
        const int tile = x4 >> 1;
        const int vb   = (x4 & 1) * 4;
        const unsigned long long row = RT[u];
        float4 o;
        float* ov = (float*)&o;
#pragma unroll
        for (int j = 0; j < 4; ++j) {
            const unsigned r = (unsigned)((row >> (8 * (vb + j))) & 0xFFull);
            const float v = smp[tile * 17 + (int)(r & 15u)];
            ov[j] = (r != 0xFFu) ? v : 0.0f;
        }
        *(float4*)(out + obase + (long long)u * W + x4 * 4) = o;
    }
}

__global__ __launch_bounds__(256) void reduce_kernel(
    const float2* __restrict__ partials,
    float* __restrict__ out)
{
    const int t = threadIdx.x;
    float s1 = 0.f, s2 = 0.f;
    for (int i = t; i < NBLK; i += 256) {
        const float2 v = partials[i];
        s1 += v.x;
        s2 += v.y;
    }
#pragma unroll
    for (int off = 32; off > 0; off >>= 1) {
        s1 += __shfl_xor(s1, off, 64);
        s2 += __shfl_xor(s2, off, 64);
    }
    __shared__ float a1[4], a2[4];
    if ((t & 63) == 0) { a1[t >> 6] = s1; a2[t >> 6] = s2; }
    __syncthreads();
    if (t == 0) {
        const float S1 = a1[0] + a1[1] + a1[2] + a1[3];  // sum eps^2
        const float S2 = a2[0] + a2[1] + a2[2] + a2[3];  // sum log_std
        out[CHW]     = -0.5f * S1 - S2 - 0.5f * NTOT * LOG2PI;
        out[CHW + 1] = 0.5f * (1.0f + LOG2PI) * NTOT + S2;
    }
}

extern "C" void kernel_launch(void* const* d_in, const int* in_sizes, int n_in,
                              void* d_out, int out_size, void* d_ws, size_t ws_size,
                              hipStream_t stream) {
    const float* mean    = (const float*)d_in[0];
    const float* log_std = (const float*)d_in[1];
    const float* eps     = (const float*)d_in[2];
    float* out = (float*)d_out;
    float2* partials = (float2*)d_ws;   // 12288 * 8 B = 96 KiB

    dct_policy_kernel<<<NBLK, 256, 0, stream>>>(mean, log_std, eps, out, partials);
    reduce_kernel<<<1, 256, 0, stream>>>(partials, out);
}